// Round 6
// baseline (289.715 us; speedup 1.0000x reference)
//
#include <hip/hip_runtime.h>
#include <hip/hip_bf16.h>

#define D 128
#define BSH 8                      // 256 nodes per bucket
#define BMASK 255
#define CSTRIDE 32                 // bucket cursors padded to 1 per 128B line

typedef __attribute__((ext_vector_type(8))) short bf16x8;
typedef __attribute__((ext_vector_type(4))) float f32x4;
typedef unsigned short u16;
typedef unsigned int u32;

// fp32 -> bf16 round-to-nearest-even, bit-level
__device__ inline u16 f2bf(float f) {
    union { float f; u32 u; } v; v.f = f;
    u32 r = v.u + 0x7FFFu + ((v.u >> 16) & 1u);
    return (u16)(r >> 16);
}

// ---------------------------------------------------------------------------
// fp32 -> bf16 cast of three arrays + bucket-cursor init, one launch.
// ---------------------------------------------------------------------------
__global__ void cast3_kernel(const float* __restrict__ a, const float* __restrict__ b,
                             const float* __restrict__ c, u16* __restrict__ oa,
                             u16* __restrict__ ob, u16* __restrict__ oc,
                             int na4, int nw4,
                             int* __restrict__ bCursor, int nbuk, int cap) {
    int i = blockIdx.x * blockDim.x + threadIdx.x;
    if (i < nbuk) bCursor[i * CSTRIDE] = i * cap;    // fixed-stride bucket bases
    const float* in; u16* out; int k;
    if (i < na4)                { in = a; out = oa; k = i; }
    else if (i < na4 + nw4)     { in = b; out = ob; k = i - na4; }
    else if (i < na4 + 2 * nw4) { in = c; out = oc; k = i - na4 - nw4; }
    else return;
    float4 v = *(const float4*)(in + (size_t)k * 4);
    u32 lo = (u32)f2bf(v.x) | ((u32)f2bf(v.y) << 16);
    u32 hi = (u32)f2bf(v.z) | ((u32)f2bf(v.w) << 16);
    *(uint2*)(out + (size_t)k * 4) = make_uint2(lo, hi);
}

// ---------------------------------------------------------------------------
// Partition edges into fixed-stride buckets (bucket b owns temp[b*cap ..)).
// ---------------------------------------------------------------------------
__global__ void partition_kernel(const int* __restrict__ src, const int* __restrict__ dst,
                                 const float* __restrict__ w, int* __restrict__ bucketCursor,
                                 uint2* __restrict__ temp, int E, int nbuk) {
    __shared__ int cnt[1024];
    __shared__ int base[1024];
    int per = (E + gridDim.x - 1) / gridDim.x;
    int lo = blockIdx.x * per;
    int hi = min(E, lo + per);
    for (int i = threadIdx.x; i < nbuk; i += blockDim.x) cnt[i] = 0;
    __syncthreads();
    for (int i = lo + threadIdx.x; i < hi; i += blockDim.x)
        atomicAdd(&cnt[src[i] >> BSH], 1);
    __syncthreads();
    for (int i = threadIdx.x; i < nbuk; i += blockDim.x)
        base[i] = cnt[i] ? atomicAdd(&bucketCursor[i * CSTRIDE], cnt[i]) : 0;
    __syncthreads();
    for (int i = threadIdx.x; i < nbuk; i += blockDim.x) cnt[i] = 0;
    __syncthreads();
    for (int i = lo + threadIdx.x; i < hi; i += blockDim.x) {
        int s = src[i];
        int b = s >> BSH;
        int off = atomicAdd(&cnt[b], 1);
        temp[base[b] + off] =
            make_uint2((u32)dst[i] | ((u32)(s & BMASK) << 17), __float_as_uint(w[i]));
    }
}

// ---------------------------------------------------------------------------
// Per-bucket CSR finalize.
// ---------------------------------------------------------------------------
__global__ void bucket_csr(const uint2* __restrict__ temp, const int* __restrict__ bucketEnd,
                           uint2* __restrict__ rowse, uint2* __restrict__ edge,
                           int N, int cap) {
    int b = blockIdx.x;
    int lo = b * cap;
    int hi = bucketEnd[b * CSTRIDE];
    int t = threadIdx.x;
    __shared__ int deg_l[256];
    __shared__ int sc[256];
    __shared__ int cur[256];
    deg_l[t] = 0;
    __syncthreads();
    for (int i = lo + t; i < hi; i += 256)
        atomicAdd(&deg_l[temp[i].x >> 17], 1);
    __syncthreads();
    int mydeg = deg_l[t];
    sc[t] = mydeg;
    __syncthreads();
    for (int off = 1; off < 256; off <<= 1) {
        int v = (t >= off) ? sc[t - off] : 0;
        __syncthreads();
        sc[t] += v;
        __syncthreads();
    }
    int excl = (t == 0) ? 0 : sc[t - 1];
    int gnode = (b << BSH) + t;
    if (gnode < N) rowse[gnode] = make_uint2((u32)(lo + excl), (u32)mydeg);
    cur[t] = excl;
    __syncthreads();
    for (int i = lo + t; i < hi; i += 256) {
        uint2 r = temp[i];                     // L2-hot
        int p = atomicAdd(&cur[r.x >> 17], 1);
        edge[lo + p] = make_uint2(r.x & 0x1FFFFu, r.y);
    }
}

// ---------------------------------------------------------------------------
// FUSED aggregate + SAGE GEMM. 128 rows/block, 512 threads (8 waves x 16
// rows). Removes the neighB global round-trip (51.2MB/layer) and 2 launches;
// finer tiles fix the 391-block 2:1 CU imbalance (grid 782, 2 blocks/CU).
//
// LDS (64KB peak):
//   [0,32K)  neigh: 128 rows x 256B, 16B slots XOR-swizzled: slot j stored at
//            j ^ (row&15)  (write conflict-free; MFMA read 4-way, ok)
//   [32K,64K) B half-K: 128 cols x 128k bf16, slot kc at kc ^ (col&15)
//
// Phases: stage B0 | aggregate 16 own nodes -> LDS | issue A-x + B1 loads |
//   barrier | MFMA k=0..127 | barrier | B1 regs->LDS | barrier |
//   MFMA k=128..255 (A-neigh via swizzled ds_read) | barrier | epilogue.
// Numerics identical to split version: neigh rounded to bf16 via f2bf.
// ---------------------------------------------------------------------------
template <bool NORM>
__global__ void __launch_bounds__(512, 4)
sage_fused(const u16* __restrict__ feat,   // gather table AND self-features
           const uint2* __restrict__ rowse,
           const uint2* __restrict__ edge,
           const u16* __restrict__ Wb,     // [128][256] bf16
           const float* __restrict__ bias, // [128]
           u16* __restrict__ outB,         // NORM=false
           float* __restrict__ outF,       // NORM=true
           int n) {
    __shared__ __attribute__((aligned(16))) char smem[65536];
    const char* fb = (const char*)feat;

    const int tid  = threadIdx.x;
    const int wave = tid >> 6;
    const int lane = tid & 63;
    const int grp  = lane >> 4;
    const int l16  = lane & 15;
    const int r0   = blockIdx.x * 128;

    // ---- P0: stage B half 0 (k 0..127) into LDS[32K..64K) ----
#pragma unroll
    for (int it = 0; it < 4; ++it) {
        int e  = it * 512 + tid;          // 2048 chunks = 128 cols x 16 kc
        int c2 = e >> 4;
        int kc = e & 15;
        uint4 v = *(const uint4*)(Wb + (size_t)c2 * 256 + kc * 8);
        *(uint4*)(smem + 32768 + c2 * 256 + ((u32)(kc ^ (c2 & 15)) << 4)) = v;
    }

    // ---- P1: aggregate this wave's 16 nodes into LDS neigh ----
    {
        int ndl = r0 + wave * 16 + l16;
        if (ndl > n - 1) ndl = n - 1;
        uint2 seL = rowse[ndl];           // lanes 0..15 hold nodes 0..15 (dup per quad)
#pragma unroll 1
        for (int i = 0; i < 16; ++i) {
            int beg = __builtin_amdgcn_readfirstlane(__shfl((int)seL.x, i));
            int deg = __builtin_amdgcn_readfirstlane(__shfl((int)seL.y, i));
            int end = beg + deg;
            float acc[8] = {0.f, 0.f, 0.f, 0.f, 0.f, 0.f, 0.f, 0.f};
            float ws = 0.f;
            for (int j = beg; j < end; j += 16) {     // 4 gathers in flight
                int i0 = j + grp, i1 = j + 4 + grp, i2 = j + 8 + grp, i3 = j + 12 + grp;
                int c0 = i0 < end ? i0 : end - 1;
                int c1 = i1 < end ? i1 : end - 1;
                int c2 = i2 < end ? i2 : end - 1;
                int c3 = i3 < end ? i3 : end - 1;
                uint2 e0 = edge[c0], e1 = edge[c1], e2 = edge[c2], e3 = edge[c3];
                float w0 = (i0 < end) ? __uint_as_float(e0.y) : 0.f;
                float w1 = (i1 < end) ? __uint_as_float(e1.y) : 0.f;
                float w2 = (i2 < end) ? __uint_as_float(e2.y) : 0.f;
                float w3 = (i3 < end) ? __uint_as_float(e3.y) : 0.f;
                uint4 u0 = *(const uint4*)(fb + (size_t)e0.x * 256u + (u32)l16 * 16u);
                uint4 u1 = *(const uint4*)(fb + (size_t)e1.x * 256u + (u32)l16 * 16u);
                uint4 u2 = *(const uint4*)(fb + (size_t)e2.x * 256u + (u32)l16 * 16u);
                uint4 u3 = *(const uint4*)(fb + (size_t)e3.x * 256u + (u32)l16 * 16u);
                u32 a0[4] = {u0.x, u0.y, u0.z, u0.w};
                u32 a1[4] = {u1.x, u1.y, u1.z, u1.w};
                u32 a2[4] = {u2.x, u2.y, u2.z, u2.w};
                u32 a3[4] = {u3.x, u3.y, u3.z, u3.w};
#pragma unroll
                for (int kk = 0; kk < 4; ++kk) {
                    acc[kk * 2]     += __uint_as_float(a0[kk] << 16) * w0
                                     + __uint_as_float(a1[kk] << 16) * w1
                                     + __uint_as_float(a2[kk] << 16) * w2
                                     + __uint_as_float(a3[kk] << 16) * w3;
                    acc[kk * 2 + 1] += __uint_as_float(a0[kk] & 0xFFFF0000u) * w0
                                     + __uint_as_float(a1[kk] & 0xFFFF0000u) * w1
                                     + __uint_as_float(a2[kk] & 0xFFFF0000u) * w2
                                     + __uint_as_float(a3[kk] & 0xFFFF0000u) * w3;
                }
                ws += w0 + w1 + w2 + w3;
            }
#pragma unroll
            for (int kk = 0; kk < 8; ++kk) {
                acc[kk] += __shfl_xor(acc[kk], 16);
                acc[kk] += __shfl_xor(acc[kk], 32);
            }
            ws += __shfl_xor(ws, 16);
            ws += __shfl_xor(ws, 32);
            float inv = 1.0f / fmaxf(ws, 1e-12f);
            if (grp == 0) {
                u32 o0 = (u32)f2bf(acc[0] * inv) | ((u32)f2bf(acc[1] * inv) << 16);
                u32 o1 = (u32)f2bf(acc[2] * inv) | ((u32)f2bf(acc[3] * inv) << 16);
                u32 o2 = (u32)f2bf(acc[4] * inv) | ((u32)f2bf(acc[5] * inv) << 16);
                u32 o3 = (u32)f2bf(acc[6] * inv) | ((u32)f2bf(acc[7] * inv) << 16);
                int lr = wave * 16 + i;
                *(uint4*)(smem + lr * 256 + ((u32)(l16 ^ (lr & 15)) << 4)) =
                    make_uint4(o0, o1, o2, o3);
            }
        }
    }

    // ---- P2: issue A-x (k 0..127) and B half-1 loads; in flight over barrier ----
    bf16x8 ax[4];
    {
        int ra = r0 + wave * 16 + l16;
        if (ra >= n) ra = n - 1;
        const u16* pax = feat + (size_t)ra * D + (lane >> 4) * 8;
#pragma unroll
        for (int kk = 0; kk < 4; ++kk)
            ax[kk] = *(const bf16x8*)(pax + kk * 32);
    }
    uint4 breg[4];
#pragma unroll
    for (int it = 0; it < 4; ++it) {
        int e  = it * 512 + tid;
        int c2 = e >> 4;
        int kc = e & 15;
        breg[it] = *(const uint4*)(Wb + (size_t)c2 * 256 + 128 + kc * 8);
    }

    __syncthreads();

    // ---- P3: MFMA k=0..127 (A-x regs, B0 LDS) ----
    const int quad = lane >> 4;
    f32x4 acc[8];
#pragma unroll
    for (int c = 0; c < 8; ++c) acc[c] = (f32x4){0.f, 0.f, 0.f, 0.f};

#pragma unroll
    for (int kk = 0; kk < 4; ++kk) {
        u32 slot = ((u32)(kk * 4 + quad) ^ (u32)l16) << 4;
#pragma unroll
        for (int c = 0; c < 8; ++c) {
            bf16x8 b = *(const bf16x8*)(smem + 32768 + (c * 16 + l16) * 256 + slot);
            acc[c] = __builtin_amdgcn_mfma_f32_16x16x32_bf16(ax[kk], b, acc[c], 0, 0, 0);
        }
    }

    __syncthreads();                     // all B0 reads done

    // ---- P4: write B half-1 into LDS ----
#pragma unroll
    for (int it = 0; it < 4; ++it) {
        int e  = it * 512 + tid;
        int c2 = e >> 4;
        int kc = e & 15;
        *(uint4*)(smem + 32768 + c2 * 256 + ((u32)(kc ^ (c2 & 15)) << 4)) = breg[it];
    }
    __syncthreads();

    // ---- P5: MFMA k=128..255 (A-neigh LDS, B1 LDS) ----
#pragma unroll
    for (int kk = 0; kk < 4; ++kk) {
        u32 slot = ((u32)(kk * 4 + quad) ^ (u32)l16) << 4;
        bf16x8 an = *(const bf16x8*)(smem + (wave * 16 + l16) * 256 + slot);
#pragma unroll
        for (int c = 0; c < 8; ++c) {
            bf16x8 b = *(const bf16x8*)(smem + 32768 + (c * 16 + l16) * 256 + slot);
            acc[c] = __builtin_amdgcn_mfma_f32_16x16x32_bf16(an, b, acc[c], 0, 0, 0);
        }
    }

    __syncthreads();                     // smem dead; reuse for epilogue staging

    // ---- Epilogue: C/D layout col=l16, row=quad*4+reg; coalesced stores ----
    float bvals[8];
#pragma unroll
    for (int c = 0; c < 8; ++c) bvals[c] = bias[c * 16 + l16];

    if (NORM) {
        float* stg = (float*)smem + wave * 2048;     // 8KB per wave, 64KB total
#pragma unroll
        for (int reg = 0; reg < 4; ++reg) {
            float v[8];
#pragma unroll
            for (int c = 0; c < 8; ++c)
                v[c] = fmaxf(acc[c][reg] + bvals[c], 0.0f);
            float ss = 0.f;
#pragma unroll
            for (int c = 0; c < 8; ++c) ss += v[c] * v[c];
            ss += __shfl_xor(ss, 1);
            ss += __shfl_xor(ss, 2);
            ss += __shfl_xor(ss, 4);
            ss += __shfl_xor(ss, 8);
            float inv = 1.0f / fmaxf(sqrtf(ss), 1e-12f);
#pragma unroll
            for (int c = 0; c < 8; ++c)
                stg[(quad * 4 + reg) * 128 + c * 16 + l16] = v[c] * inv;
        }
#pragma unroll
        for (int p = 0; p < 8; ++p) {                // 16 rows x 512B, 2 rows/instr
            int lr = 2 * p + (lane >> 5);
            int grow = r0 + wave * 16 + lr;
            float4 val = *(float4*)&stg[lr * 128 + (lane & 31) * 4];
            if (grow < n)
                *(float4*)(outF + (size_t)grow * D + (lane & 31) * 4) = val;
        }
    } else {
        u16* stg = (u16*)smem + wave * 2048;         // 4KB per wave
#pragma unroll
        for (int reg = 0; reg < 4; ++reg) {
#pragma unroll
            for (int c = 0; c < 8; ++c) {
                float v = fmaxf(acc[c][reg] + bvals[c], 0.0f);
                stg[(quad * 4 + reg) * 128 + c * 16 + l16] = f2bf(v);
            }
        }
#pragma unroll
        for (int p = 0; p < 4; ++p) {                // 16 rows x 256B, 4 rows/instr
            int lr = 4 * p + (lane >> 4);
            int grow = r0 + wave * 16 + lr;
            uint4 val = *(uint4*)&stg[lr * 128 + l16 * 8];
            if (grow < n)
                *(uint4*)(outB + (size_t)grow * D + l16 * 8) = val;
        }
    }
}

extern "C" void kernel_launch(void* const* d_in, const int* in_sizes, int n_in,
                              void* d_out, int out_size, void* d_ws, size_t ws_size,
                              hipStream_t stream) {
    const float* x  = (const float*)d_in[0];
    const int*   ei = (const int*)d_in[1];   // [2, E]: row 0 = src, row 1 = dst
    const float* ew = (const float*)d_in[2];
    const float* W1 = (const float*)d_in[3];
    const float* b1 = (const float*)d_in[4];
    const float* W2 = (const float*)d_in[5];
    const float* b2 = (const float*)d_in[6];
    float* out = (float*)d_out;

    const int E = in_sizes[2];
    const int N = in_sizes[0] / D;
    const int nbuk = (N + BMASK) >> BSH;                 // 391 for N=100000
    const int CAP = ((2 * (E / nbuk + 1) + 1023) / 1024) * 1024;  // 4096

    const int* src = ei;
    const int* dst = ei + E;

    // workspace layout
    char* p = (char*)d_ws;
    auto alloc = [&](size_t bytes) { char* r = p; p += (bytes + 255) & ~(size_t)255; return r; };
    u16*   xb      = (u16*)  alloc((size_t)N * D * sizeof(u16));          // 25.6 MB
    u16*   hB      = (u16*)  alloc((size_t)N * D * sizeof(u16));          // 25.6 MB
    uint2* temp    = (uint2*)alloc(((size_t)nbuk * CAP + 64) * 8);        // 12.8 MB
    uint2* edge    = (uint2*)alloc(((size_t)nbuk * CAP + 64) * 8);        // 12.8 MB
    u16*   Wb1     = (u16*)  alloc((size_t)D * 2 * D * sizeof(u16));
    u16*   Wb2     = (u16*)  alloc((size_t)D * 2 * D * sizeof(u16));
    uint2* rowse   = (uint2*)alloc((size_t)N * sizeof(uint2));
    int*   bCursor = (int*)  alloc((size_t)(nbuk * CSTRIDE + 64) * sizeof(int));

    const int fusedGrid = (N + 127) / 128;   // 782: 2 resident blocks/CU, low tail
    const int n4 = N * D / 4;
    const int w4 = D * 2 * D / 4;   // 8192
    const int castTotal = n4 + 2 * w4;

    // ---- casts + cursor init, then bucket partition + per-bucket CSR ----
    cast3_kernel    <<<(castTotal + 255) / 256, 256, 0, stream>>>(x, W1, W2, xb, Wb1, Wb2,
                                                                  n4, w4, bCursor, nbuk, CAP);
    partition_kernel<<<256, 256, 0, stream>>>(src, dst, ew, bCursor, temp, E, nbuk);
    bucket_csr      <<<nbuk, 256, 0, stream>>>(temp, bCursor, rowse, edge, N, CAP);

    // ---- Layer 1 (aggregate fused into GEMM) ----
    sage_fused<false><<<fusedGrid, 512, 0, stream>>>(xb, rowse, edge, Wb1, b1,
                                                     hB, nullptr, N);
    // ---- Layer 2 (normalize fused into epilogue) ----
    sage_fused<true><<<fusedGrid, 512, 0, stream>>>(hB, rowse, edge, Wb2, b2,
                                                    nullptr, out, N);
}

// Round 7
// 249.214 us; speedup vs baseline: 1.1625x; 1.1625x over previous
//
#include <hip/hip_runtime.h>
#include <hip/hip_bf16.h>

#define D 128
#define BSH 8                      // 256 nodes per bucket
#define BMASK 255
#define CSTRIDE 32                 // bucket cursors padded to 1 per 128B line

typedef __attribute__((ext_vector_type(8))) short bf16x8;
typedef __attribute__((ext_vector_type(4))) float f32x4;
typedef unsigned short u16;
typedef unsigned int u32;

// fp32 -> bf16 round-to-nearest-even, bit-level
__device__ inline u16 f2bf(float f) {
    union { float f; u32 u; } v; v.f = f;
    u32 r = v.u + 0x7FFFu + ((v.u >> 16) & 1u);
    return (u16)(r >> 16);
}

// ---------------------------------------------------------------------------
// fp32 -> bf16 cast of three arrays + bucket-cursor init, one launch.
// ---------------------------------------------------------------------------
__global__ void cast3_kernel(const float* __restrict__ a, const float* __restrict__ b,
                             const float* __restrict__ c, u16* __restrict__ oa,
                             u16* __restrict__ ob, u16* __restrict__ oc,
                             int na4, int nw4,
                             int* __restrict__ bCursor, int nbuk, int cap) {
    int i = blockIdx.x * blockDim.x + threadIdx.x;
    if (i < nbuk) bCursor[i * CSTRIDE] = i * cap;    // fixed-stride bucket bases
    const float* in; u16* out; int k;
    if (i < na4)                { in = a; out = oa; k = i; }
    else if (i < na4 + nw4)     { in = b; out = ob; k = i - na4; }
    else if (i < na4 + 2 * nw4) { in = c; out = oc; k = i - na4 - nw4; }
    else return;
    float4 v = *(const float4*)(in + (size_t)k * 4);
    u32 lo = (u32)f2bf(v.x) | ((u32)f2bf(v.y) << 16);
    u32 hi = (u32)f2bf(v.z) | ((u32)f2bf(v.w) << 16);
    *(uint2*)(out + (size_t)k * 4) = make_uint2(lo, hi);
}

// ---------------------------------------------------------------------------
// Partition edges into fixed-stride buckets (bucket b owns temp[b*cap ..)).
// Widened to 1024 threads/block (16 waves/CU): the 256-thread version ran at
// ~4 waves/CU with ~12 latency-exposed strided iterations per phase.
// ---------------------------------------------------------------------------
__global__ void __launch_bounds__(1024)
partition_kernel(const int* __restrict__ src, const int* __restrict__ dst,
                 const float* __restrict__ w, int* __restrict__ bucketCursor,
                 uint2* __restrict__ temp, int E, int nbuk) {
    __shared__ int cnt[1024];
    __shared__ int base[1024];
    int per = (E + gridDim.x - 1) / gridDim.x;
    int lo = blockIdx.x * per;
    int hi = min(E, lo + per);
    for (int i = threadIdx.x; i < nbuk; i += blockDim.x) cnt[i] = 0;
    __syncthreads();
    for (int i = lo + threadIdx.x; i < hi; i += blockDim.x)
        atomicAdd(&cnt[src[i] >> BSH], 1);
    __syncthreads();
    for (int i = threadIdx.x; i < nbuk; i += blockDim.x)
        base[i] = cnt[i] ? atomicAdd(&bucketCursor[i * CSTRIDE], cnt[i]) : 0;
    __syncthreads();
    for (int i = threadIdx.x; i < nbuk; i += blockDim.x) cnt[i] = 0;
    __syncthreads();
    for (int i = lo + threadIdx.x; i < hi; i += blockDim.x) {
        int s = src[i];
        int b = s >> BSH;
        int off = atomicAdd(&cnt[b], 1);
        temp[base[b] + off] =
            make_uint2((u32)dst[i] | ((u32)(s & BMASK) << 17), __float_as_uint(w[i]));
    }
}

// ---------------------------------------------------------------------------
// Per-bucket CSR finalize. Widened to 1024 threads/block: edge passes stride
// 1024 (per-thread iterations 8 -> 2); node-scan sections guarded t<256 with
// all-thread barriers. Intra-node edge order nondeterminism unchanged in kind.
// ---------------------------------------------------------------------------
__global__ void __launch_bounds__(1024)
bucket_csr(const uint2* __restrict__ temp, const int* __restrict__ bucketEnd,
           uint2* __restrict__ rowse, uint2* __restrict__ edge,
           int N, int cap) {
    int b = blockIdx.x;
    int lo = b * cap;
    int hi = bucketEnd[b * CSTRIDE];
    int t = threadIdx.x;
    __shared__ int deg_l[256];
    __shared__ int sc[256];
    __shared__ int cur[256];
    if (t < 256) deg_l[t] = 0;
    __syncthreads();
    for (int i = lo + t; i < hi; i += 1024)
        atomicAdd(&deg_l[temp[i].x >> 17], 1);
    __syncthreads();
    int mydeg = (t < 256) ? deg_l[t] : 0;
    if (t < 256) sc[t] = mydeg;
    __syncthreads();
    for (int off = 1; off < 256; off <<= 1) {
        int v = 0;
        if (t < 256 && t >= off) v = sc[t - off];
        __syncthreads();
        if (t < 256) sc[t] += v;
        __syncthreads();
    }
    if (t < 256) {
        int excl = (t == 0) ? 0 : sc[t - 1];
        int gnode = (b << BSH) + t;
        if (gnode < N) rowse[gnode] = make_uint2((u32)(lo + excl), (u32)mydeg);
        cur[t] = excl;
    }
    __syncthreads();
    for (int i = lo + t; i < hi; i += 1024) {
        uint2 r = temp[i];                     // L2-hot
        int p = atomicAdd(&cur[r.x >> 17], 1);
        edge[lo + p] = make_uint2(r.x & 0x1FFFFu, r.y);
    }
}

// ---------------------------------------------------------------------------
// Gather aggregation v2: lane-group gather. 4 groups x 16 lanes per wave;
// each group owns one edge slot, 16B/lane dwordx4 -> one VMEM covers 4
// edges' full 256B rows. At the L3 random-gather limit for this access
// pattern (v1 and v2 structures measured identical).
// ---------------------------------------------------------------------------
__global__ void aggregate_kernel(const u16* __restrict__ feat,
                                 const uint2* __restrict__ rowse,
                                 const uint2* __restrict__ edge,
                                 u16* __restrict__ neigh, int n) {
    const char* fb = (const char*)feat;
    int wv   = blockIdx.x * 4 + (threadIdx.x >> 6);
    int lane = threadIdx.x & 63;
    int grp  = lane >> 4;          // edge slot within wave
    int l16  = lane & 15;          // owns dims l16*8 .. l16*8+7
    int node0 = wv * 4;
    if (node0 >= n) return;

    int begs[4], degs[4];
#pragma unroll
    for (int i = 0; i < 4; ++i) {
        int nd = node0 + i; if (nd > n - 1) nd = n - 1;
        uint2 se = rowse[nd];
        begs[i] = __builtin_amdgcn_readfirstlane((int)se.x);
        degs[i] = __builtin_amdgcn_readfirstlane((int)se.y);
    }

#pragma unroll 1
    for (int i = 0; i < 4; ++i) {
        int node = node0 + i;
        if (node >= n) break;
        int beg = begs[i];
        int end = beg + degs[i];
        float acc[8] = {0.f, 0.f, 0.f, 0.f, 0.f, 0.f, 0.f, 0.f};
        float ws = 0.f;
        for (int j = beg; j < end; j += 8) {
            int ia = j + grp;
            int ib = j + 4 + grp;
            int ca = ia < end ? ia : end - 1;    // deg==0 never enters loop
            int cb = ib < end ? ib : end - 1;
            uint2 ea = edge[ca];
            uint2 eb = edge[cb];
            float wa = (ia < end) ? __uint_as_float(ea.y) : 0.f;
            float wb = (ib < end) ? __uint_as_float(eb.y) : 0.f;
            uint4 ua = *(const uint4*)(fb + (size_t)ea.x * 256u + (u32)l16 * 16u);
            uint4 ub = *(const uint4*)(fb + (size_t)eb.x * 256u + (u32)l16 * 16u);
            u32 va[4] = {ua.x, ua.y, ua.z, ua.w};
            u32 vb[4] = {ub.x, ub.y, ub.z, ub.w};
#pragma unroll
            for (int kk = 0; kk < 4; ++kk) {
                acc[kk * 2]     += __uint_as_float(va[kk] << 16) * wa
                                 + __uint_as_float(vb[kk] << 16) * wb;
                acc[kk * 2 + 1] += __uint_as_float(va[kk] & 0xFFFF0000u) * wa
                                 + __uint_as_float(vb[kk] & 0xFFFF0000u) * wb;
            }
            ws += wa + wb;
        }
        // sum the 4 lane-group partials (lane ^16, ^32)
#pragma unroll
        for (int kk = 0; kk < 8; ++kk) {
            acc[kk] += __shfl_xor(acc[kk], 16);
            acc[kk] += __shfl_xor(acc[kk], 32);
        }
        ws += __shfl_xor(ws, 16);
        ws += __shfl_xor(ws, 32);
        float inv = 1.0f / fmaxf(ws, 1e-12f);
        if (grp == 0) {                          // 16 lanes x 16B = 256B row
            u32 o0 = (u32)f2bf(acc[0] * inv) | ((u32)f2bf(acc[1] * inv) << 16);
            u32 o1 = (u32)f2bf(acc[2] * inv) | ((u32)f2bf(acc[3] * inv) << 16);
            u32 o2 = (u32)f2bf(acc[4] * inv) | ((u32)f2bf(acc[5] * inv) << 16);
            u32 o3 = (u32)f2bf(acc[6] * inv) | ((u32)f2bf(acc[7] * inv) << 16);
            *(uint4*)(neigh + (size_t)node * D + l16 * 8) = make_uint4(o0, o1, o2, o3);
        }
    }
}

// ---------------------------------------------------------------------------
// Fused SAGE GEMM v3 — barrier-free streaming structure for tall-skinny shape.
// K=256 total, B = 128x256 bf16 = 64KB -> entire B lives in LDS (one barrier).
// Each wave owns 32 rows: whole A-slice loaded straight to registers
// (16x global_load_dwordx4 in flight, no LDS staging, no per-iteration
// barriers, no vmcnt(0) drains). B is XOR-swizzled against the 16-way
// conflict of 512B-stride column reads.
// ---------------------------------------------------------------------------
template <bool NORM>
__global__ void __launch_bounds__(512, 2)
sage_gemm(const u16* __restrict__ axb,
          const u16* __restrict__ aneigh,
          const u16* __restrict__ Wb,      // [128][256] bf16
          const float* __restrict__ bias,  // [128]
          u16* __restrict__ outB,          // NORM=false
          float* __restrict__ outF,        // NORM=true
          int n) {
    __shared__ __attribute__((aligned(16))) char smem[65536];   // B, then out-stage

    const int tid  = threadIdx.x;
    const int wave = tid >> 6;
    const int lane = tid & 63;
    const int quad = lane >> 4;
    const int l16  = lane & 15;
    const int r0   = blockIdx.x * 256 + wave * 32;   // this wave's 32 rows

    // ---- A: 16 direct global->reg loads, whole K for two 16-row strips ----
    bf16x8 a[2][8];
    {
        int ra = r0 + l16;        if (ra >= n) ra = n - 1;   // clamp; never stored
        int rb = r0 + 16 + l16;   if (rb >= n) rb = n - 1;
        const u16* p00 = axb    + (size_t)ra * D + quad * 8;
        const u16* p10 = axb    + (size_t)rb * D + quad * 8;
        const u16* p01 = aneigh + (size_t)ra * D + quad * 8;
        const u16* p11 = aneigh + (size_t)rb * D + quad * 8;
#pragma unroll
        for (int kk = 0; kk < 4; ++kk) {
            a[0][kk] = *(const bf16x8*)(p00 + kk * 32);
            a[1][kk] = *(const bf16x8*)(p10 + kk * 32);
        }
#pragma unroll
        for (int kk = 0; kk < 4; ++kk) {
            a[0][4 + kk] = *(const bf16x8*)(p01 + kk * 32);
            a[1][4 + kk] = *(const bf16x8*)(p11 + kk * 32);
        }
    }

    // ---- stage whole B into LDS, XOR-swizzled, 64KB ----
#pragma unroll
    for (int it = 0; it < 8; ++it) {
        int e = it * 512 + tid;          // 4096 chunks = 128 cols x 32 k-chunks
        int c  = e >> 5;
        int kc = e & 31;
        uint4 v = *(const uint4*)(Wb + (size_t)c * 256 + kc * 8);
        u32 off = (((u32)c << 9) + ((u32)kc << 4)) ^ (((u32)c & 7u) << 4);
        *(uint4*)(smem + off) = v;
    }
    __syncthreads();                     // the ONLY barrier before the epilogue

    // ---- MFMA loop: consume A-regs in issue order (compiler counts vmcnt) ----
    f32x4 acc[2][8];
#pragma unroll
    for (int s = 0; s < 2; ++s)
#pragma unroll
        for (int c = 0; c < 8; ++c)
            acc[s][c] = (f32x4){0.f, 0.f, 0.f, 0.f};

#pragma unroll
    for (int kk = 0; kk < 8; ++kk) {
#pragma unroll
        for (int c = 0; c < 8; ++c) {
            u32 col = (u32)(c * 16 + l16);
            u32 off = ((col << 9) + ((u32)(kk * 4 + quad) << 4)) ^ ((col & 7u) << 4);
            bf16x8 b = *(const bf16x8*)(smem + off);
            acc[0][c] = __builtin_amdgcn_mfma_f32_16x16x32_bf16(a[0][kk], b, acc[0][c], 0, 0, 0);
            acc[1][c] = __builtin_amdgcn_mfma_f32_16x16x32_bf16(a[1][kk], b, acc[1][c], 0, 0, 0);
        }
    }

    __syncthreads();                     // B dead; smem reused for output staging

    // ---- Epilogue: C/D layout col=l16, row=quad*4+reg. Stage per-wave in
    // LDS, store fully coalesced 16B/lane. ----
    float bvals[8];
#pragma unroll
    for (int c = 0; c < 8; ++c) bvals[c] = bias[c * 16 + l16];

    if (NORM) {
        float* stg = (float*)smem + wave * 2048;     // 8KB per wave
#pragma unroll
        for (int s = 0; s < 2; ++s) {
#pragma unroll
            for (int reg = 0; reg < 4; ++reg) {
                float v[8];
#pragma unroll
                for (int c = 0; c < 8; ++c)
                    v[c] = fmaxf(acc[s][c][reg] + bvals[c], 0.0f);
                float ss = 0.f;
#pragma unroll
                for (int c = 0; c < 8; ++c) ss += v[c] * v[c];
                ss += __shfl_xor(ss, 1);
                ss += __shfl_xor(ss, 2);
                ss += __shfl_xor(ss, 4);
                ss += __shfl_xor(ss, 8);
                float inv = 1.0f / fmaxf(sqrtf(ss), 1e-12f);
#pragma unroll
                for (int c = 0; c < 8; ++c)
                    stg[(quad * 4 + reg) * 128 + c * 16 + l16] = v[c] * inv;
            }
#pragma unroll
            for (int p = 0; p < 8; ++p) {            // 16 rows x 512B, 2 rows/instr
                int lr = 2 * p + (lane >> 5);
                int grow = r0 + s * 16 + lr;
                float4 val = *(float4*)&stg[lr * 128 + (lane & 31) * 4];
                if (grow < n)
                    *(float4*)(outF + (size_t)grow * D + (lane & 31) * 4) = val;
            }
        }
    } else {
        u16* stg = (u16*)smem + wave * 2048;         // 4KB per wave
#pragma unroll
        for (int s = 0; s < 2; ++s) {
#pragma unroll
            for (int reg = 0; reg < 4; ++reg) {
#pragma unroll
                for (int c = 0; c < 8; ++c) {
                    float v = fmaxf(acc[s][c][reg] + bvals[c], 0.0f);
                    stg[(quad * 4 + reg) * 128 + c * 16 + l16] = f2bf(v);
                }
            }
#pragma unroll
            for (int p = 0; p < 4; ++p) {            // 16 rows x 256B, 4 rows/instr
                int lr = 4 * p + (lane >> 4);
                int grow = r0 + s * 16 + lr;
                uint4 val = *(uint4*)&stg[lr * 128 + l16 * 8];
                if (grow < n)
                    *(uint4*)(outB + (size_t)grow * D + l16 * 8) = val;
            }
        }
    }
}

extern "C" void kernel_launch(void* const* d_in, const int* in_sizes, int n_in,
                              void* d_out, int out_size, void* d_ws, size_t ws_size,
                              hipStream_t stream) {
    const float* x  = (const float*)d_in[0];
    const int*   ei = (const int*)d_in[1];   // [2, E]: row 0 = src, row 1 = dst
    const float* ew = (const float*)d_in[2];
    const float* W1 = (const float*)d_in[3];
    const float* b1 = (const float*)d_in[4];
    const float* W2 = (const float*)d_in[5];
    const float* b2 = (const float*)d_in[6];
    float* out = (float*)d_out;

    const int E = in_sizes[2];
    const int N = in_sizes[0] / D;
    const int nbuk = (N + BMASK) >> BSH;                 // 391 for N=100000
    const int CAP = ((2 * (E / nbuk + 1) + 1023) / 1024) * 1024;  // 4096

    const int* src = ei;
    const int* dst = ei + E;

    // workspace layout
    char* p = (char*)d_ws;
    auto alloc = [&](size_t bytes) { char* r = p; p += (bytes + 255) & ~(size_t)255; return r; };
    u16*   xb      = (u16*)  alloc((size_t)N * D * sizeof(u16));          // 25.6 MB
    u16*   hB      = (u16*)  alloc((size_t)N * D * sizeof(u16));          // 25.6 MB
    u16*   neighB  = (u16*)  alloc((size_t)N * D * sizeof(u16));          // 25.6 MB
    uint2* temp    = (uint2*)alloc(((size_t)nbuk * CAP + 64) * 8);        // 12.8 MB
    uint2* edge    = (uint2*)alloc(((size_t)nbuk * CAP + 64) * 8);        // 12.8 MB
    u16*   Wb1     = (u16*)  alloc((size_t)D * 2 * D * sizeof(u16));
    u16*   Wb2     = (u16*)  alloc((size_t)D * 2 * D * sizeof(u16));
    uint2* rowse   = (uint2*)alloc((size_t)N * sizeof(uint2));
    int*   bCursor = (int*)  alloc((size_t)(nbuk * CSTRIDE + 64) * sizeof(int));

    const int gemmGrid = (N + 255) / 256;
    const int n4 = N * D / 4;
    const int w4 = D * 2 * D / 4;   // 8192
    const int castTotal = n4 + 2 * w4;
    const int aggGrid = (N + 15) / 16;    // 4 nodes/wave x 4 waves/block

    // ---- casts + cursor init, then bucket partition + per-bucket CSR ----
    cast3_kernel    <<<(castTotal + 255) / 256, 256, 0, stream>>>(x, W1, W2, xb, Wb1, Wb2,
                                                                  n4, w4, bCursor, nbuk, CAP);
    partition_kernel<<<256, 1024, 0, stream>>>(src, dst, ew, bCursor, temp, E, nbuk);
    bucket_csr      <<<nbuk, 1024, 0, stream>>>(temp, bCursor, rowse, edge, N, CAP);

    // ---- Layer 1 ----
    aggregate_kernel<<<aggGrid, 256, 0, stream>>>(xb, rowse, edge, neighB, N);
    sage_gemm<false><<<gemmGrid, 512, 0, stream>>>(xb, neighB, Wb1, b1, hB, nullptr, N);

    // ---- Layer 2 (normalize fused into epilogue) ----
    aggregate_kernel<<<aggGrid, 256, 0, stream>>>(hB, rowse, edge, neighB, N);
    sage_gemm<true><<<gemmGrid, 512, 0, stream>>>(hB, neighB, Wb2, b2, nullptr, out, N);
}